// Round 11
// baseline (239.141 us; speedup 1.0000x reference)
//
#include <hip/hip_runtime.h>
#include <math.h>

// Problem constants
#define BATCH   8
#define SEQ     1024
#define HIDDEN  1024
#define NHEADS  16
#define HDIM    64
#define MROWS   (BATCH * SEQ)        // 8192

typedef __bf16 bf16x8 __attribute__((ext_vector_type(8)));
typedef float  f32x4  __attribute__((ext_vector_type(4)));

__device__ __forceinline__ unsigned short f2bf(float f) {
    union { float f; unsigned int u; } v; v.f = f;
    unsigned int u = v.u;
    u += 0x7fffu + ((u >> 16) & 1u);   // round-to-nearest-even
    return (unsigned short)(u >> 16);
}

// pack hi16 of two floats (truncating bf16 convert)
__device__ __forceinline__ unsigned int pack2bf_trunc(float a, float b) {
    union { float f; unsigned int u; } ua, ub;
    ua.f = a; ub.f = b;
    return (ua.u >> 16) | (ub.u & 0xFFFF0000u);
}

// async global->LDS, 16B per lane; lds dst = wave-uniform base + lane*16
__device__ __forceinline__ void gl2lds16(const unsigned short* g, unsigned short* l) {
    __builtin_amdgcn_global_load_lds(
        (const __attribute__((address_space(1))) void*)g,
        (__attribute__((address_space(3))) void*)l, 16, 0, 0);
}

// ---------------------------------------------------------------------------
// Fused prep kernel (one launch instead of three):
//   blocks [0, 8192)        : query fp32 -> bf16 convert (float4/ushort4)
//   blocks [8192, 11264)    : w_qkv [1024][3072] -> bf16 [3072][1024] transpose
//   blocks [11264, 12288)   : w_o   [1024][1024] -> bf16 [1024][1024] transpose
// ---------------------------------------------------------------------------
__global__ __launch_bounds__(256) void prep_kernel(
    const float* __restrict__ query, unsigned short* __restrict__ queryBf,
    const float* __restrict__ wqkv,  unsigned short* __restrict__ wqkvT,
    const float* __restrict__ wo,    unsigned short* __restrict__ woT) {
    __shared__ float tile[32][33];
    const int bid = blockIdx.x;
    const int tid = threadIdx.x;

    if (bid < 8192) {
        int i = bid * 256 + tid;
        float4 v = reinterpret_cast<const float4*>(query)[i];
        ushort4 o;
        o.x = f2bf(v.x); o.y = f2bf(v.y); o.z = f2bf(v.z); o.w = f2bf(v.w);
        reinterpret_cast<ushort4*>(queryBf)[i] = o;
        return;
    }

    const float* in;
    unsigned short* out;
    int R, C, bx, by;
    if (bid < 8192 + 3072) {
        int b = bid - 8192;
        in = wqkv; out = wqkvT; R = HIDDEN; C = 3 * HIDDEN;
        bx = b % 96; by = b / 96;
    } else {
        int b = bid - 11264;
        in = wo; out = woT; R = HIDDEN; C = HIDDEN;
        bx = b % 32; by = b / 32;
    }
    const int tx = tid & 31, ty = tid >> 5;   // 32 x 8
    const int x  = bx * 32 + tx;
    const int y0 = by * 32;
#pragma unroll
    for (int j = 0; j < 32; j += 8)
        tile[ty + j][tx] = in[(size_t)(y0 + ty + j) * C + x];
    __syncthreads();
    const int x2 = y0 + tx;
    const int y2 = bx * 32;
#pragma unroll
    for (int j = 0; j < 32; j += 8)
        out[(size_t)(y2 + ty + j) * R + x2] = f2bf(tile[tx][ty + j]);
}

// ---------------------------------------------------------------------------
// bf16 GEMM: C[M][N] = A[M][K] * Bt[N][K]^T + bias[N]
// 128x128 tile, BK=64, 4 waves (2x2), 16x16x32 MFMA. (QKV projection;
// 1536 blocks = 6/CU -> implicit wave overlap covers the stage drain.)
// EPI=0: scatter Q,K as [head][s][d] bf16 (q pre-scaled), V directly
//   transposed as [head][d][s].
// ---------------------------------------------------------------------------
template <int EPI>
__global__ __launch_bounds__(256) void gemm_bt_kernel(
    const unsigned short* __restrict__ A,
    const unsigned short* __restrict__ Bt,
    const float* __restrict__ bias,
    unsigned short* __restrict__ out_bf,
    float* __restrict__ out_f,
    int M, int N, int K) {
    __shared__ __align__(16) unsigned short As[128 * 64];
    __shared__ __align__(16) unsigned short Bs[128 * 64];

    const int tid  = threadIdx.x;
    const int wid  = tid >> 6;
    const int lane = tid & 63;
    const int l15  = lane & 15;
    const int quad = lane >> 4;
    const int wm   = (wid & 1) * 64;
    const int wn   = (wid >> 1) * 64;

    const int npn = N >> 7;
    const int pid = blockIdx.x;
    const int ppg = 4 * npn;              // pids per group
    const int gid = pid / ppg;
    const int loc = pid - gid * ppg;
    const int pm  = gid * 4 + (loc & 3);
    const int pn  = loc >> 2;
    const int m0  = pm * 128;
    const int n0  = pn * 128;

    const int srow = wid * 32 + (lane >> 3);            // + it*8
    const int skcs = ((lane & 7) ^ (lane >> 3)) * 8;    // swizzled chunk offset
    const int rsw  = lane & 7;

    f32x4 acc[4][4];
#pragma unroll
    for (int i = 0; i < 4; ++i)
#pragma unroll
        for (int j = 0; j < 4; ++j) acc[i][j] = (f32x4){0.f, 0.f, 0.f, 0.f};

    for (int kt = 0; kt < K; kt += 64) {
        __syncthreads();
#pragma unroll
        for (int it = 0; it < 4; ++it) {
            int row = srow + it * 8;
            gl2lds16(A  + (size_t)(m0 + row) * K + kt + skcs, As + (wid * 32 + it * 8) * 64);
            gl2lds16(Bt + (size_t)(n0 + row) * K + kt + skcs, Bs + (wid * 32 + it * 8) * 64);
        }
        __syncthreads();
#pragma unroll
        for (int ks = 0; ks < 2; ++ks) {
            bf16x8 afr[4], bfr[4];
#pragma unroll
            for (int i = 0; i < 4; ++i)
                afr[i] = *reinterpret_cast<const bf16x8*>(
                    As + (wm + i * 16 + l15) * 64 + ((ks * 4 + quad) ^ rsw) * 8);
#pragma unroll
            for (int j = 0; j < 4; ++j)
                bfr[j] = *reinterpret_cast<const bf16x8*>(
                    Bs + (wn + j * 16 + l15) * 64 + ((ks * 4 + quad) ^ rsw) * 8);
#pragma unroll
            for (int i = 0; i < 4; ++i)
#pragma unroll
                for (int j = 0; j < 4; ++j)
                    acc[i][j] = __builtin_amdgcn_mfma_f32_16x16x32_bf16(afr[i], bfr[j], acc[i][j], 0, 0, 0);
        }
    }

#pragma unroll
    for (int j = 0; j < 4; ++j) {
        int col   = n0 + wn + j * 16 + l15;
        float bv  = bias[col];
        if constexpr (EPI == 0) {
            int which = col >> 10;
            int rem   = col & 1023;
            int h     = rem >> 6, d = rem & 63;
            if (which == 2) {
                // V -> V^T scatter: [bh][d][s], 4 contiguous s per ushort4
#pragma unroll
                for (int i = 0; i < 4; ++i) {
                    int row0 = m0 + wm + i * 16 + quad * 4;
                    int b    = row0 >> 10, s0 = row0 & 1023;
                    ushort4 o;
                    o.x = f2bf(acc[i][j][0] + bv);
                    o.y = f2bf(acc[i][j][1] + bv);
                    o.z = f2bf(acc[i][j][2] + bv);
                    o.w = f2bf(acc[i][j][3] + bv);
                    size_t idx = ((size_t)(2 * BATCH * NHEADS) +
                                  (size_t)b * NHEADS + h) * (SEQ * HDIM) +
                                 (size_t)d * SEQ + s0;
                    *reinterpret_cast<ushort4*>(out_bf + idx) = o;
                }
            } else {
                // Q pre-scale folds head_dim^-0.5 and log2(e) for exp2 softmax
                float sc = (which == 0) ? 0.18033688011112042f : 1.0f;
#pragma unroll
                for (int i = 0; i < 4; ++i)
#pragma unroll
                    for (int r = 0; r < 4; ++r) {
                        int row = m0 + wm + i * 16 + quad * 4 + r;
                        int b   = row >> 10, s = row & 1023;
                        float v = (acc[i][j][r] + bv) * sc;
                        size_t idx = ((((size_t)which * BATCH + b) * NHEADS + h) * SEQ + s) * HDIM + d;
                        out_bf[idx] = f2bf(v);
                    }
            }
        } else {
#pragma unroll
            for (int i = 0; i < 4; ++i)
#pragma unroll
                for (int r = 0; r < 4; ++r) {
                    int row = m0 + wm + i * 16 + quad * 4 + r;
                    out_f[(size_t)row * N + col] = acc[i][j][r] + bv;
                }
        }
    }
}

// ---------------------------------------------------------------------------
// ROUND 11 NEW: double-buffered 128x128 GEMM for the output projection.
// gemm2 measured 66.4us for 17.2 GFLOP (258 TF) vs gemm1's 775 TF on
// IDENTICAL code -- the difference is residency (512 blocks = 2/CU vs
// 1536 = 6/CU): at 2/CU the per-K-tile vmcnt(0)+barrier stage drain has
// almost no other-block compute to hide under (m114 implicit overlap
// needs >=3 blocks/CU; m99/m100's dbuf-null was measured at ~3/CU).
// Explicit dbuf is FREE here: As[2]+Bs[2] = 64KB still fits 2 blocks/CU.
// Pattern = round-6 attn: stage(t+1 -> buf^1) issued BEFORE compute(t),
// one __syncthreads per K-tile (auto vmcnt-drain lands after a full
// compute phase of overlap; WAR on buf^1 barrier-separated).
// fp32 out + bias epilogue only.
// ---------------------------------------------------------------------------
__global__ __launch_bounds__(256) void gemm_bt_db_kernel(
    const unsigned short* __restrict__ A,
    const unsigned short* __restrict__ Bt,
    const float* __restrict__ bias,
    float* __restrict__ out_f,
    int M, int N, int K) {
    __shared__ __align__(16) unsigned short As[2][128 * 64];
    __shared__ __align__(16) unsigned short Bs[2][128 * 64];

    const int tid  = threadIdx.x;
    const int wid  = tid >> 6;
    const int lane = tid & 63;
    const int l15  = lane & 15;
    const int quad = lane >> 4;
    const int wm   = (wid & 1) * 64;
    const int wn   = (wid >> 1) * 64;

    const int npn = N >> 7;
    const int pid = blockIdx.x;
    const int ppg = 4 * npn;
    const int gid = pid / ppg;
    const int loc = pid - gid * ppg;
    const int pm  = gid * 4 + (loc & 3);
    const int pn  = loc >> 2;
    const int m0  = pm * 128;
    const int n0  = pn * 128;

    const int srow = wid * 32 + (lane >> 3);
    const int skcs = ((lane & 7) ^ (lane >> 3)) * 8;
    const int rsw  = lane & 7;

    auto stage = [&](int kt, int buf) {
#pragma unroll
        for (int it = 0; it < 4; ++it) {
            int row = srow + it * 8;
            gl2lds16(A  + (size_t)(m0 + row) * K + kt + skcs,
                     As[buf] + (wid * 32 + it * 8) * 64);
            gl2lds16(Bt + (size_t)(n0 + row) * K + kt + skcs,
                     Bs[buf] + (wid * 32 + it * 8) * 64);
        }
    };

    f32x4 acc[4][4];
#pragma unroll
    for (int i = 0; i < 4; ++i)
#pragma unroll
        for (int j = 0; j < 4; ++j) acc[i][j] = (f32x4){0.f, 0.f, 0.f, 0.f};

    const int NT = K >> 6;   // 16
    stage(0, 0);
    __syncthreads();          // auto vmcnt-drain: tile 0 resident

    for (int t = 0; t < NT; ++t) {
        const int cur = t & 1;
        if (t + 1 < NT) stage((t + 1) * 64, cur ^ 1);   // overlaps compute(t)

#pragma unroll
        for (int ks = 0; ks < 2; ++ks) {
            bf16x8 afr[4], bfr[4];
#pragma unroll
            for (int i = 0; i < 4; ++i)
                afr[i] = *reinterpret_cast<const bf16x8*>(
                    As[cur] + (wm + i * 16 + l15) * 64 + ((ks * 4 + quad) ^ rsw) * 8);
#pragma unroll
            for (int j = 0; j < 4; ++j)
                bfr[j] = *reinterpret_cast<const bf16x8*>(
                    Bs[cur] + (wn + j * 16 + l15) * 64 + ((ks * 4 + quad) ^ rsw) * 8);
#pragma unroll
            for (int i = 0; i < 4; ++i)
#pragma unroll
                for (int j = 0; j < 4; ++j)
                    acc[i][j] = __builtin_amdgcn_mfma_f32_16x16x32_bf16(afr[i], bfr[j], acc[i][j], 0, 0, 0);
        }

        // one barrier per K-tile: drains next tile's stage (issued a full
        // compute phase ago) + WAR guard for buf^1 reuse
        __syncthreads();
    }

#pragma unroll
    for (int j = 0; j < 4; ++j) {
        int col   = n0 + wn + j * 16 + l15;
        float bv  = bias[col];
#pragma unroll
        for (int i = 0; i < 4; ++i)
#pragma unroll
            for (int r = 0; r < 4; ++r) {
                int row = m0 + wm + i * 16 + quad * 4 + r;
                out_f[(size_t)row * N + col] = acc[i][j][r] + bv;
            }
    }
}

// ---------------------------------------------------------------------------
// Flash attention, raw-exp2 softmax. (Round-10 config: 4 waves x 64 q-rows,
// K/V dbuf, K row>>3-keyed swizzle, Q/V row&7, raw v_exp_f32. Round 10
// showed 32- and 64-row variants equivalent; keeping 64-row.)
// ---------------------------------------------------------------------------
__global__ __launch_bounds__(256, 2) void attn_kernel(
    const unsigned short* __restrict__ qkv,
    const unsigned short* __restrict__ vt,   // [head][d][s]
    unsigned short* __restrict__ x) {
    constexpr int LDP = 68;
    __shared__ __align__(16) unsigned short Ks[2][64 * 64];   // [key][d], (row>>3) swizzle
    __shared__ __align__(16) unsigned short Vs[2][64 * 64];   // [d][key], (row&7) swizzle
    __shared__ __align__(16) unsigned short PQ[4][64 * LDP];  // P per wave; aliases Q stage

    unsigned short* Qs = &PQ[0][0];   // 256*64 shorts = 32KB <= 34.8KB region

    const int tid  = threadIdx.x;
    const int wid  = tid >> 6;        // 0..3
    const int lane = tid & 63;
    const int l15  = lane & 15;
    const int quad = lane >> 4;
    const int srow8 = lane >> 3;
    const int skcs  = ((lane & 7) ^ srow8) * 8;
    const int rsw   = lane & 7;

    // XCD-aware swizzle: id&7 = xcd; q-block fastest, head slowest
    const int id = blockIdx.x;                 // 0..511
    const int bh = (id & 7) * 16 + (id >> 5);  // head: 16 heads per XCD
    const int q0 = ((id >> 3) & 3) * 256;      // 4 q-blocks x 256 rows

    const unsigned short* Qg  = qkv + (size_t)bh * SEQ * HDIM;
    const unsigned short* Kg  = qkv + (size_t)(128 + bh) * SEQ * HDIM;
    const unsigned short* VTg = vt + (size_t)bh * SEQ * HDIM;   // [d][s]

    // stage K/V tile t0s into buffer buf: 4 waves x 16 rows each
    auto stageKV = [&](int t0s, int buf) {
#pragma unroll
        for (int it = 0; it < 2; ++it) {
            int row = wid * 16 + it * 8 + srow8;   // 0..63
            int sK  = ((lane & 7) ^ (wid * 2 + it)) * 8;   // (row>>3)-keyed, wave-uniform
            gl2lds16(Kg + (size_t)(t0s + row) * HDIM + sK,
                     Ks[buf] + (wid * 16 + it * 8) * 64);
            gl2lds16(VTg + (size_t)row * SEQ + t0s + skcs,
                     Vs[buf] + (wid * 16 + it * 8) * 64);
        }
    };

    // prologue: stage Q (256 x 64) into P-aliased region + K/V tile 0
#pragma unroll
    for (int it = 0; it < 8; ++it) {
        gl2lds16(Qg + (size_t)(q0 + wid * 64 + it * 8 + srow8) * HDIM + skcs,
                 Qs + (wid * 64 + it * 8) * 64);
    }
    stageKV(0, 0);
    __syncthreads();   // auto vmcnt-drain: Q + tile0 resident

    bf16x8 qf[4][2];
#pragma unroll
    for (int m = 0; m < 4; ++m)
#pragma unroll
        for (int h = 0; h < 2; ++h)
            qf[m][h] = *reinterpret_cast<const bf16x8*>(
                Qs + (wid * 64 + m * 16 + l15) * 64 + ((h * 4 + quad) ^ rsw) * 8);
    __syncthreads();   // all waves done reading Q region -> PQ writable

    float lsum[4][4];
    f32x4 accO[4][4];
#pragma unroll
    for (int m = 0; m < 4; ++m)
#pragma unroll
        for (int r = 0; r < 4; ++r) lsum[m][r] = 0.f;
#pragma unroll
    for (int m = 0; m < 4; ++m)
#pragma unroll
        for (int jd = 0; jd < 4; ++jd) accO[m][jd] = (f32x4){0.f, 0.f, 0.f, 0.f};

    for (int t0 = 0; t0 < SEQ; t0 += 64) {
        const int cur = (t0 >> 6) & 1;
        // issue next tile's staging into the other buffer; hides under compute
        if (t0 + 64 < SEQ) stageKV(t0 + 64, cur ^ 1);

        // logits: 64 q-rows x 64 keys per wave; MFMA j feeds K-row l15*4+j
        f32x4 accL[4][4];
#pragma unroll
        for (int m = 0; m < 4; ++m)
#pragma unroll
            for (int j = 0; j < 4; ++j) accL[m][j] = (f32x4){0.f, 0.f, 0.f, 0.f};
#pragma unroll
        for (int j = 0; j < 4; ++j) {
            int krow = l15 * 4 + j;
            int kru  = krow >> 3;                // row>>3 read key (= l15>>1)
            bf16x8 kf0 = *reinterpret_cast<const bf16x8*>(
                Ks[cur] + krow * 64 + ((0 + quad) ^ kru) * 8);
            bf16x8 kf1 = *reinterpret_cast<const bf16x8*>(
                Ks[cur] + krow * 64 + ((4 + quad) ^ kru) * 8);
#pragma unroll
            for (int m = 0; m < 4; ++m) {
                accL[m][j] = __builtin_amdgcn_mfma_f32_16x16x32_bf16(qf[m][0], kf0, accL[m][j], 0, 0, 0);
                accL[m][j] = __builtin_amdgcn_mfma_f32_16x16x32_bf16(qf[m][1], kf1, accL[m][j], 0, 0, 0);
            }
        }

        // raw-exp2 softmax: p = exp2(logit); accL[m][j][r] = key l15*4+j.
#pragma unroll
        for (int m = 0; m < 4; ++m)
#pragma unroll
            for (int r = 0; r < 4; ++r) {
                float p0 = __builtin_amdgcn_exp2f(accL[m][0][r]);
                float p1 = __builtin_amdgcn_exp2f(accL[m][1][r]);
                float p2 = __builtin_amdgcn_exp2f(accL[m][2][r]);
                float p3 = __builtin_amdgcn_exp2f(accL[m][3][r]);
                lsum[m][r] += (p0 + p1) + (p2 + p3);
                uint2 pk;
                pk.x = pack2bf_trunc(p0, p1);
                pk.y = pack2bf_trunc(p2, p3);
                *reinterpret_cast<uint2*>(
                    &PQ[wid][(m * 16 + quad * 4 + r) * LDP + l15 * 4]) = pk;
            }

        // PV: P[64 x 64] (A-layout, natural key order) * V^T[d][key] (B-layout)
        bf16x8 pf[4][2];
#pragma unroll
        for (int m = 0; m < 4; ++m)
#pragma unroll
            for (int h = 0; h < 2; ++h)
                pf[m][h] = *reinterpret_cast<const bf16x8*>(
                    PQ[wid] + (m * 16 + l15) * LDP + h * 32 + quad * 8);
#pragma unroll
        for (int jd = 0; jd < 4; ++jd) {
            bf16x8 vf0 = *reinterpret_cast<const bf16x8*>(
                Vs[cur] + (jd * 16 + l15) * 64 + ((0 + quad) ^ rsw) * 8);
            bf16x8 vf1 = *reinterpret_cast<const bf16x8*>(
                Vs[cur] + (jd * 16 + l15) * 64 + ((4 + quad) ^ rsw) * 8);
#pragma unroll
            for (int m = 0; m < 4; ++m) {
                accO[m][jd] = __builtin_amdgcn_mfma_f32_16x16x32_bf16(pf[m][0], vf0, accO[m][jd], 0, 0, 0);
                accO[m][jd] = __builtin_amdgcn_mfma_f32_16x16x32_bf16(pf[m][1], vf1, accO[m][jd], 0, 0, 0);
            }
        }

        // single per-tile barrier: auto vmcnt-drain (next tile resident)
        // + WAR guard (all waves done reading Ks/Vs[cur] and their own PQ)
        __syncthreads();
    }

    // final row-sum reduce (once) + epilogue
    const int b = bh >> 4, h = bh & 15;
#pragma unroll
    for (int m = 0; m < 4; ++m)
#pragma unroll
        for (int r = 0; r < 4; ++r) {
            float s = lsum[m][r];
            s += __shfl_xor(s, 1);
            s += __shfl_xor(s, 2);
            s += __shfl_xor(s, 4);
            s += __shfl_xor(s, 8);
            float inv = 1.0f / s;
            int srow = q0 + wid * 64 + m * 16 + quad * 4 + r;
            size_t base = ((size_t)b * SEQ + srow) * HIDDEN + h * HDIM;
#pragma unroll
            for (int jd = 0; jd < 4; ++jd)
                x[base + jd * 16 + l15] = f2bf(accO[m][jd][r] * inv);
        }
}

// ---------------------------------------------------------------------------
extern "C" void kernel_launch(void* const* d_in, const int* in_sizes, int n_in,
                              void* d_out, int out_size, void* d_ws, size_t ws_size,
                              hipStream_t stream) {
    const float* query = (const float*)d_in[0];
    const float* w_qkv = (const float*)d_in[1];
    const float* b_qkv = (const float*)d_in[2];
    const float* w_o   = (const float*)d_in[3];
    const float* b_o   = (const float*)d_in[4];
    float* out = (float*)d_out;

    unsigned short* ws = (unsigned short*)d_ws;
    unsigned short* queryBf = ws;                                  // 8192*1024
    unsigned short* wqkvT   = queryBf + (size_t)MROWS * HIDDEN;    // 3072*1024
    unsigned short* woT     = wqkvT + (size_t)3 * HIDDEN * HIDDEN; // 1024*1024
    unsigned short* qkvbuf  = woT + (size_t)HIDDEN * HIDDEN;       // 3*8192*1024
    unsigned short* xbuf    = qkvbuf + (size_t)3 * MROWS * HIDDEN; // 8192*1024
    // V region of qkvbuf holds V^T [head][d][s], written directly by gemm1
    unsigned short* vtbuf   = qkvbuf + (size_t)2 * BATCH * NHEADS * SEQ * HDIM;

    // fused prep: query cvt (8192 blocks) + w_qkv T (3072) + w_o T (1024)
    prep_kernel<<<dim3(12288), 256, 0, stream>>>(
        query, queryBf, w_qkv, wqkvT, w_o, woT);

    // QKV projection; V scattered pre-transposed (no transpose_v kernel)
    gemm_bt_kernel<0><<<dim3((MROWS / 128) * (3 * HIDDEN / 128)), 256, 0, stream>>>(
        queryBf, wqkvT, b_qkv, qkvbuf, nullptr, MROWS, 3 * HIDDEN, HIDDEN);

    // attention: 512 blocks x 256 threads (4 waves x 64 q-rows per block)
    attn_kernel<<<dim3(512), 256, 0, stream>>>(qkvbuf, vtbuf, xbuf);

    // output projection: double-buffered 128^2 (2 blocks/CU -> dbuf is free
    // in occupancy and covers the stage drain that 2/CU can't hide)
    gemm_bt_db_kernel<<<dim3((MROWS / 128) * (HIDDEN / 128)), 256, 0, stream>>>(
        xbuf, woT, b_o, out, MROWS, HIDDEN, HIDDEN);
}

// Round 12
// 223.899 us; speedup vs baseline: 1.0681x; 1.0681x over previous
//
#include <hip/hip_runtime.h>
#include <math.h>

// Problem constants
#define BATCH   8
#define SEQ     1024
#define HIDDEN  1024
#define NHEADS  16
#define HDIM    64
#define MROWS   (BATCH * SEQ)        // 8192

typedef __bf16 bf16x8 __attribute__((ext_vector_type(8)));
typedef float  f32x4  __attribute__((ext_vector_type(4)));

__device__ __forceinline__ unsigned short f2bf(float f) {
    union { float f; unsigned int u; } v; v.f = f;
    unsigned int u = v.u;
    u += 0x7fffu + ((u >> 16) & 1u);   // round-to-nearest-even
    return (unsigned short)(u >> 16);
}

// pack hi16 of two floats (truncating bf16 convert)
__device__ __forceinline__ unsigned int pack2bf_trunc(float a, float b) {
    union { float f; unsigned int u; } ua, ub;
    ua.f = a; ub.f = b;
    return (ua.u >> 16) | (ub.u & 0xFFFF0000u);
}

// async global->LDS, 16B per lane; lds dst = wave-uniform base + lane*16
__device__ __forceinline__ void gl2lds16(const unsigned short* g, unsigned short* l) {
    __builtin_amdgcn_global_load_lds(
        (const __attribute__((address_space(1))) void*)g,
        (__attribute__((address_space(3))) void*)l, 16, 0, 0);
}

// ---------------------------------------------------------------------------
// Fused prep kernel (one launch instead of three):
//   blocks [0, 8192)        : query fp32 -> bf16 convert (float4/ushort4)
//   blocks [8192, 11264)    : w_qkv [1024][3072] -> bf16 [3072][1024] transpose
//   blocks [11264, 12288)   : w_o   [1024][1024] -> bf16 [1024][1024] transpose
// ---------------------------------------------------------------------------
__global__ __launch_bounds__(256) void prep_kernel(
    const float* __restrict__ query, unsigned short* __restrict__ queryBf,
    const float* __restrict__ wqkv,  unsigned short* __restrict__ wqkvT,
    const float* __restrict__ wo,    unsigned short* __restrict__ woT) {
    __shared__ float tile[32][33];
    const int bid = blockIdx.x;
    const int tid = threadIdx.x;

    if (bid < 8192) {
        int i = bid * 256 + tid;
        float4 v = reinterpret_cast<const float4*>(query)[i];
        ushort4 o;
        o.x = f2bf(v.x); o.y = f2bf(v.y); o.z = f2bf(v.z); o.w = f2bf(v.w);
        reinterpret_cast<ushort4*>(queryBf)[i] = o;
        return;
    }

    const float* in;
    unsigned short* out;
    int R, C, bx, by;
    if (bid < 8192 + 3072) {
        int b = bid - 8192;
        in = wqkv; out = wqkvT; R = HIDDEN; C = 3 * HIDDEN;
        bx = b % 96; by = b / 96;
    } else {
        int b = bid - 11264;
        in = wo; out = woT; R = HIDDEN; C = HIDDEN;
        bx = b % 32; by = b / 32;
    }
    const int tx = tid & 31, ty = tid >> 5;   // 32 x 8
    const int x  = bx * 32 + tx;
    const int y0 = by * 32;
#pragma unroll
    for (int j = 0; j < 32; j += 8)
        tile[ty + j][tx] = in[(size_t)(y0 + ty + j) * C + x];
    __syncthreads();
    const int x2 = y0 + tx;
    const int y2 = bx * 32;
#pragma unroll
    for (int j = 0; j < 32; j += 8)
        out[(size_t)(y2 + ty + j) * R + x2] = f2bf(tile[tx][ty + j]);
}

// ---------------------------------------------------------------------------
// bf16 GEMM: C[M][N] = A[M][K] * Bt[N][K]^T + bias[N]
// 128x128 tile, BK=64, 4 waves (2x2), 16x16x32 MFMA.
// EPI=0 (QKV projection): scatter Q,K as [head][s][d] bf16 (q pre-scaled),
//   V directly transposed as [head][d][s].
// EPI=1 (output projection): fp32 out[M][N]. NOTE (r11 post-mortem): the
//   "gemm2 = 66us" NaN rows in r8-r10 profiles were gemm1's second rocprof
//   pass (WRITE ~50.8MB = EPI=0 signature); gemm2 never appeared in any
//   top-5 -> it is < 66us. The r11 dbuf variant attacked a phantom and is
//   reverted.
// ---------------------------------------------------------------------------
template <int EPI>
__global__ __launch_bounds__(256) void gemm_bt_kernel(
    const unsigned short* __restrict__ A,
    const unsigned short* __restrict__ Bt,
    const float* __restrict__ bias,
    unsigned short* __restrict__ out_bf,
    float* __restrict__ out_f,
    int M, int N, int K) {
    __shared__ __align__(16) unsigned short As[128 * 64];
    __shared__ __align__(16) unsigned short Bs[128 * 64];

    const int tid  = threadIdx.x;
    const int wid  = tid >> 6;
    const int lane = tid & 63;
    const int l15  = lane & 15;
    const int quad = lane >> 4;
    const int wm   = (wid & 1) * 64;
    const int wn   = (wid >> 1) * 64;

    const int npn = N >> 7;
    const int pid = blockIdx.x;
    const int ppg = 4 * npn;              // pids per group
    const int gid = pid / ppg;
    const int loc = pid - gid * ppg;
    const int pm  = gid * 4 + (loc & 3);
    const int pn  = loc >> 2;
    const int m0  = pm * 128;
    const int n0  = pn * 128;

    const int srow = wid * 32 + (lane >> 3);            // + it*8
    const int skcs = ((lane & 7) ^ (lane >> 3)) * 8;    // swizzled chunk offset
    const int rsw  = lane & 7;

    f32x4 acc[4][4];
#pragma unroll
    for (int i = 0; i < 4; ++i)
#pragma unroll
        for (int j = 0; j < 4; ++j) acc[i][j] = (f32x4){0.f, 0.f, 0.f, 0.f};

    for (int kt = 0; kt < K; kt += 64) {
        __syncthreads();
#pragma unroll
        for (int it = 0; it < 4; ++it) {
            int row = srow + it * 8;
            gl2lds16(A  + (size_t)(m0 + row) * K + kt + skcs, As + (wid * 32 + it * 8) * 64);
            gl2lds16(Bt + (size_t)(n0 + row) * K + kt + skcs, Bs + (wid * 32 + it * 8) * 64);
        }
        __syncthreads();
#pragma unroll
        for (int ks = 0; ks < 2; ++ks) {
            bf16x8 afr[4], bfr[4];
#pragma unroll
            for (int i = 0; i < 4; ++i)
                afr[i] = *reinterpret_cast<const bf16x8*>(
                    As + (wm + i * 16 + l15) * 64 + ((ks * 4 + quad) ^ rsw) * 8);
#pragma unroll
            for (int j = 0; j < 4; ++j)
                bfr[j] = *reinterpret_cast<const bf16x8*>(
                    Bs + (wn + j * 16 + l15) * 64 + ((ks * 4 + quad) ^ rsw) * 8);
#pragma unroll
            for (int i = 0; i < 4; ++i)
#pragma unroll
                for (int j = 0; j < 4; ++j)
                    acc[i][j] = __builtin_amdgcn_mfma_f32_16x16x32_bf16(afr[i], bfr[j], acc[i][j], 0, 0, 0);
        }
    }

#pragma unroll
    for (int j = 0; j < 4; ++j) {
        int col   = n0 + wn + j * 16 + l15;
        float bv  = bias[col];
        if constexpr (EPI == 0) {
            int which = col >> 10;
            int rem   = col & 1023;
            int h     = rem >> 6, d = rem & 63;
            if (which == 2) {
                // V -> V^T scatter: [bh][d][s], 4 contiguous s per ushort4
#pragma unroll
                for (int i = 0; i < 4; ++i) {
                    int row0 = m0 + wm + i * 16 + quad * 4;
                    int b    = row0 >> 10, s0 = row0 & 1023;
                    ushort4 o;
                    o.x = f2bf(acc[i][j][0] + bv);
                    o.y = f2bf(acc[i][j][1] + bv);
                    o.z = f2bf(acc[i][j][2] + bv);
                    o.w = f2bf(acc[i][j][3] + bv);
                    size_t idx = ((size_t)(2 * BATCH * NHEADS) +
                                  (size_t)b * NHEADS + h) * (SEQ * HDIM) +
                                 (size_t)d * SEQ + s0;
                    *reinterpret_cast<ushort4*>(out_bf + idx) = o;
                }
            } else {
                // Q pre-scale folds head_dim^-0.5 and log2(e) for exp2 softmax
                float sc = (which == 0) ? 0.18033688011112042f : 1.0f;
#pragma unroll
                for (int i = 0; i < 4; ++i)
#pragma unroll
                    for (int r = 0; r < 4; ++r) {
                        int row = m0 + wm + i * 16 + quad * 4 + r;
                        int b   = row >> 10, s = row & 1023;
                        float v = (acc[i][j][r] + bv) * sc;
                        size_t idx = ((((size_t)which * BATCH + b) * NHEADS + h) * SEQ + s) * HDIM + d;
                        out_bf[idx] = f2bf(v);
                    }
            }
        } else {
#pragma unroll
            for (int i = 0; i < 4; ++i)
#pragma unroll
                for (int r = 0; r < 4; ++r) {
                    int row = m0 + wm + i * 16 + quad * 4 + r;
                    out_f[(size_t)row * N + col] = acc[i][j][r] + bv;
                }
        }
    }
}

// ---------------------------------------------------------------------------
// Flash attention, raw-exp2 softmax. Round-9 verified config (228.08us
// session best): 512 blocks x 512 threads, 8 waves x 32 q-rows, K/V
// double-buffer, K (row>>3)-keyed swizzle, Q/V (row&7), raw v_exp_f32.
// ---------------------------------------------------------------------------
__global__ __launch_bounds__(512, 4) void attn_kernel(
    const unsigned short* __restrict__ qkv,
    const unsigned short* __restrict__ vt,   // [head][d][s]
    unsigned short* __restrict__ x) {
    constexpr int LDP = 68;
    __shared__ __align__(16) unsigned short Ks[2][64 * 64];   // [key][d], (row>>3) swizzle
    __shared__ __align__(16) unsigned short Vs[2][64 * 64];   // [d][key], (row&7) swizzle
    __shared__ __align__(16) unsigned short PQ[8][32 * LDP];  // P per wave; aliases Q stage

    unsigned short* Qs = &PQ[0][0];   // 256*64 shorts = 32KB <= 34.8KB region

    const int tid  = threadIdx.x;
    const int wid  = tid >> 6;        // 0..7
    const int lane = tid & 63;
    const int l15  = lane & 15;
    const int quad = lane >> 4;
    const int srow8 = lane >> 3;
    const int skcs  = ((lane & 7) ^ srow8) * 8;
    const int rsw   = lane & 7;

    // XCD-aware swizzle: id&7 = xcd; q-block fastest, head slowest
    const int id = blockIdx.x;                 // 0..511
    const int bh = (id & 7) * 16 + (id >> 5);  // head: 16 heads per XCD
    const int q0 = ((id >> 3) & 3) * 256;      // 4 q-blocks x 256 rows

    const unsigned short* Qg  = qkv + (size_t)bh * SEQ * HDIM;
    const unsigned short* Kg  = qkv + (size_t)(128 + bh) * SEQ * HDIM;
    const unsigned short* VTg = vt + (size_t)bh * SEQ * HDIM;   // [d][s]

    // stage K/V tile t0s into buffer buf: 8 waves x 8 rows each
    auto stageKV = [&](int t0s, int buf) {
        int row = wid * 8 + srow8;                    // 0..63
        int sK  = ((lane & 7) ^ wid) * 8;             // (row>>3)-keyed, wave-uniform
        gl2lds16(Kg + (size_t)(t0s + row) * HDIM + sK, Ks[buf] + wid * 8 * 64);
        gl2lds16(VTg + (size_t)row * SEQ + t0s + skcs, Vs[buf] + wid * 8 * 64);
    };

    // prologue: stage Q (256 x 64) into P-aliased region + K/V tile 0
#pragma unroll
    for (int it = 0; it < 4; ++it) {
        gl2lds16(Qg + (size_t)(q0 + wid * 32 + it * 8 + srow8) * HDIM + skcs,
                 Qs + (wid * 32 + it * 8) * 64);
    }
    stageKV(0, 0);
    __syncthreads();   // auto vmcnt-drain: Q + tile0 resident

    bf16x8 qf[2][2];
#pragma unroll
    for (int m = 0; m < 2; ++m)
#pragma unroll
        for (int h = 0; h < 2; ++h)
            qf[m][h] = *reinterpret_cast<const bf16x8*>(
                Qs + (wid * 32 + m * 16 + l15) * 64 + ((h * 4 + quad) ^ rsw) * 8);
    __syncthreads();   // all waves done reading Q region -> PQ writable

    float lsum[2][4];
    f32x4 accO[2][4];
#pragma unroll
    for (int m = 0; m < 2; ++m)
#pragma unroll
        for (int r = 0; r < 4; ++r) lsum[m][r] = 0.f;
#pragma unroll
    for (int m = 0; m < 2; ++m)
#pragma unroll
        for (int jd = 0; jd < 4; ++jd) accO[m][jd] = (f32x4){0.f, 0.f, 0.f, 0.f};

    for (int t0 = 0; t0 < SEQ; t0 += 64) {
        const int cur = (t0 >> 6) & 1;
        // issue next tile's staging into the other buffer; hides under compute
        if (t0 + 64 < SEQ) stageKV(t0 + 64, cur ^ 1);

        // logits: 32 q-rows x 64 keys per wave; MFMA j feeds K-row l15*4+j
        f32x4 accL[2][4];
#pragma unroll
        for (int m = 0; m < 2; ++m)
#pragma unroll
            for (int j = 0; j < 4; ++j) accL[m][j] = (f32x4){0.f, 0.f, 0.f, 0.f};
#pragma unroll
        for (int j = 0; j < 4; ++j) {
            int krow = l15 * 4 + j;
            int kru  = krow >> 3;                // row>>3 read key (= l15>>1)
            bf16x8 kf0 = *reinterpret_cast<const bf16x8*>(
                Ks[cur] + krow * 64 + ((0 + quad) ^ kru) * 8);
            bf16x8 kf1 = *reinterpret_cast<const bf16x8*>(
                Ks[cur] + krow * 64 + ((4 + quad) ^ kru) * 8);
#pragma unroll
            for (int m = 0; m < 2; ++m) {
                accL[m][j] = __builtin_amdgcn_mfma_f32_16x16x32_bf16(qf[m][0], kf0, accL[m][j], 0, 0, 0);
                accL[m][j] = __builtin_amdgcn_mfma_f32_16x16x32_bf16(qf[m][1], kf1, accL[m][j], 0, 0, 0);
            }
        }

        // raw-exp2 softmax: p = exp2(logit); accL[m][j][r] = key l15*4+j.
#pragma unroll
        for (int m = 0; m < 2; ++m)
#pragma unroll
            for (int r = 0; r < 4; ++r) {
                float p0 = __builtin_amdgcn_exp2f(accL[m][0][r]);
                float p1 = __builtin_amdgcn_exp2f(accL[m][1][r]);
                float p2 = __builtin_amdgcn_exp2f(accL[m][2][r]);
                float p3 = __builtin_amdgcn_exp2f(accL[m][3][r]);
                lsum[m][r] += (p0 + p1) + (p2 + p3);
                uint2 pk;
                pk.x = pack2bf_trunc(p0, p1);
                pk.y = pack2bf_trunc(p2, p3);
                *reinterpret_cast<uint2*>(
                    &PQ[wid][(m * 16 + quad * 4 + r) * LDP + l15 * 4]) = pk;
            }

        // PV: P[32 x 64] (A-layout, natural key order) * V^T[d][key] (B-layout)
        bf16x8 pf[2][2];
#pragma unroll
        for (int m = 0; m < 2; ++m)
#pragma unroll
            for (int h = 0; h < 2; ++h)
                pf[m][h] = *reinterpret_cast<const bf16x8*>(
                    PQ[wid] + (m * 16 + l15) * LDP + h * 32 + quad * 8);
#pragma unroll
        for (int jd = 0; jd < 4; ++jd) {
            bf16x8 vf0 = *reinterpret_cast<const bf16x8*>(
                Vs[cur] + (jd * 16 + l15) * 64 + ((0 + quad) ^ rsw) * 8);
            bf16x8 vf1 = *reinterpret_cast<const bf16x8*>(
                Vs[cur] + (jd * 16 + l15) * 64 + ((4 + quad) ^ rsw) * 8);
#pragma unroll
            for (int m = 0; m < 2; ++m) {
                accO[m][jd] = __builtin_amdgcn_mfma_f32_16x16x32_bf16(pf[m][0], vf0, accO[m][jd], 0, 0, 0);
                accO[m][jd] = __builtin_amdgcn_mfma_f32_16x16x32_bf16(pf[m][1], vf1, accO[m][jd], 0, 0, 0);
            }
        }

        // single per-tile barrier: auto vmcnt-drain (next tile resident)
        // + WAR guard (all waves done reading Ks/Vs[cur] and their own PQ)
        __syncthreads();
    }

    // final row-sum reduce (once) + epilogue
    const int b = bh >> 4, h = bh & 15;
#pragma unroll
    for (int m = 0; m < 2; ++m)
#pragma unroll
        for (int r = 0; r < 4; ++r) {
            float s = lsum[m][r];
            s += __shfl_xor(s, 1);
            s += __shfl_xor(s, 2);
            s += __shfl_xor(s, 4);
            s += __shfl_xor(s, 8);
            float inv = 1.0f / s;
            int srow = q0 + wid * 32 + m * 16 + quad * 4 + r;
            size_t base = ((size_t)b * SEQ + srow) * HIDDEN + h * HDIM;
#pragma unroll
            for (int jd = 0; jd < 4; ++jd)
                x[base + jd * 16 + l15] = f2bf(accO[m][jd][r] * inv);
        }
}

// ---------------------------------------------------------------------------
extern "C" void kernel_launch(void* const* d_in, const int* in_sizes, int n_in,
                              void* d_out, int out_size, void* d_ws, size_t ws_size,
                              hipStream_t stream) {
    const float* query = (const float*)d_in[0];
    const float* w_qkv = (const float*)d_in[1];
    const float* b_qkv = (const float*)d_in[2];
    const float* w_o   = (const float*)d_in[3];
    const float* b_o   = (const float*)d_in[4];
    float* out = (float*)d_out;

    unsigned short* ws = (unsigned short*)d_ws;
    unsigned short* queryBf = ws;                                  // 8192*1024
    unsigned short* wqkvT   = queryBf + (size_t)MROWS * HIDDEN;    // 3072*1024
    unsigned short* woT     = wqkvT + (size_t)3 * HIDDEN * HIDDEN; // 1024*1024
    unsigned short* qkvbuf  = woT + (size_t)HIDDEN * HIDDEN;       // 3*8192*1024
    unsigned short* xbuf    = qkvbuf + (size_t)3 * MROWS * HIDDEN; // 8192*1024
    // V region of qkvbuf holds V^T [head][d][s], written directly by gemm1
    unsigned short* vtbuf   = qkvbuf + (size_t)2 * BATCH * NHEADS * SEQ * HDIM;

    // fused prep: query cvt (8192 blocks) + w_qkv T (3072) + w_o T (1024)
    prep_kernel<<<dim3(12288), 256, 0, stream>>>(
        query, queryBf, w_qkv, wqkvT, w_o, woT);

    // QKV projection; V scattered pre-transposed (no transpose_v kernel)
    gemm_bt_kernel<0><<<dim3((MROWS / 128) * (3 * HIDDEN / 128)), 256, 0, stream>>>(
        queryBf, wqkvT, b_qkv, qkvbuf, nullptr, MROWS, 3 * HIDDEN, HIDDEN);

    // attention: 512 blocks x 512 threads (8 waves = 2 q-tiles per block)
    attn_kernel<<<dim3(512), 512, 0, stream>>>(qkvbuf, vtbuf, xbuf);

    // output projection: 128^2 tiles, single-buffer (r11 dbuf reverted)
    gemm_bt_kernel<1><<<dim3((MROWS / 128) * (HIDDEN / 128)), 256, 0, stream>>>(
        xbuf, woT, b_o, nullptr, out, MROWS, HIDDEN, HIDDEN);
}